// Round 6
// baseline (196.117 us; speedup 1.0000x reference)
//
#include <hip/hip_runtime.h>
#include <stdint.h>

// W4 group-quantized linear, v5: SPLITK=4 + fused tail-reduce (no reduce dispatch).
//  * Verified math from v3/v4: biased-nibble MFMA B (bf16 0x4300|n == 128+n exact),
//    k-perm sigma=[0,4,1,5,2,6,3,7] applied to both A (at cvt) and B (free),
//    per-group fold x.W = s*gacc - s*(128+z)*xsum with rounded-bf16 row sums.
//  * gemm: grid (172, 4), 256 thr = 4 waves, wave tile M32xN32 (BN=64),
//    K=1024/block = 4 stages of 256 (32KB A LDS each), 8 groups folded.
//    2752 waves (2.7/SIMD) — same occupancy as v4, half the partial traffic.
//  * Last split block per N-tile (device atomic ticket) sums the 4 partial
//    slices and writes out. cvt kernel zeroes the tickets (stream-ordered).

#define IN 4096
#define OUT 11008
#define BATCH 64
#define SPLITK 4
#define KSPL 1024
#define BN 64
#define GRID_N 172

typedef __attribute__((ext_vector_type(8))) __bf16 bf16x8;
typedef __attribute__((ext_vector_type(4))) float f32x4;

static __device__ __forceinline__ ushort f2bf(float f) {
  uint32_t u = __float_as_uint(f);
  u += 0x7fff + ((u >> 16) & 1); // RNE
  return (ushort)(u >> 16);
}
static __device__ __forceinline__ float bf2f(ushort h) {
  return __uint_as_float(((uint32_t)h) << 16);
}

// One block per quant group g. Thread t: row m = t>>2, quarter q = t&3.
// Emits xbf in A-frag-major kperm order + exact xsum[g][m]. Block 0 also
// zeroes the split-k tickets.
__global__ void cvt_frag_kernel(const float* __restrict__ x,
                                ushort* __restrict__ xbf,
                                float* __restrict__ xsum,
                                int* __restrict__ cnt) {
  const int g = blockIdx.x;
  const int t = threadIdx.x;
  if (g == 0 && t < GRID_N) cnt[t] = 0;
  const int m = t >> 2;
  const int q = t & 3;
  const int ks = 4 * g + q; // 32-wide k slab
  const int kb = 32 * ks;

  float v[32];
  ushort vb[32];
  float s = 0.f;
#pragma unroll
  for (int c4 = 0; c4 < 8; ++c4) {
    float4 f = *(const float4*)&x[m * IN + kb + 4 * c4];
    v[4 * c4 + 0] = f.x; v[4 * c4 + 1] = f.y; v[4 * c4 + 2] = f.z; v[4 * c4 + 3] = f.w;
  }
#pragma unroll
  for (int c = 0; c < 32; ++c) {
    vb[c] = f2bf(v[c]);
    s += bf2f(vb[c]);
  }
  const int i = m >> 4, mlane = m & 15;
#pragma unroll
  for (int qd = 0; qd < 4; ++qd) {
    ushort o[8];
    o[0] = vb[8 * qd + 0]; o[1] = vb[8 * qd + 4];
    o[2] = vb[8 * qd + 1]; o[3] = vb[8 * qd + 5];
    o[4] = vb[8 * qd + 2]; o[5] = vb[8 * qd + 6];
    o[6] = vb[8 * qd + 3]; o[7] = vb[8 * qd + 7];
    const int flat = (ks * 4 + i) * 64 + qd * 16 + mlane;
    *(uint4*)&xbf[flat * 8] = *(uint4*)o;
  }
  s += __shfl_xor(s, 1);
  s += __shfl_xor(s, 2);
  if (q == 0) xsum[g * 64 + m] = s;
}

__global__ __launch_bounds__(256, 3) void mpq_gemm(
    const ushort* __restrict__ xbf,    // frag-major A
    const int* __restrict__ qweight,   // [512][11008]
    const float* __restrict__ scales,  // [32][11008]
    const float* __restrict__ zeros,   // [32][11008]
    const float* __restrict__ xsum,    // [32][64]
    float* __restrict__ P,             // [4][64][11008] partials
    int* __restrict__ cnt,             // [172] tickets
    float* __restrict__ out)           // [64][11008]
{
  __shared__ uint4 A_lds[2048]; // 32 KB: [ksl 0..7][i 0..3][lane]
  __shared__ int last_flag;

  const int n0 = blockIdx.x * BN;
  const int sp = blockIdx.y;
  const int k0 = sp * KSPL;
  const int tid = threadIdx.x;
  const int lane = tid & 63;
  const int w = tid >> 6;
  const int wm = w >> 1, wn = w & 1;     // M half / N half
  const int mlane = lane & 15, quad = lane >> 4;
  const int ncol = n0 + 32 * wn + mlane; // col base (j adds 16j)

  f32x4 macc[2][2] = {};

  const uint4* gA = (const uint4*)xbf + (size_t)(k0 / 32) * 256;

  for (int h = 0; h < 4; ++h) {
    __syncthreads(); // previous stage's A reads complete
    const uint4* src = gA + (size_t)h * 2048;
#pragma unroll
    for (int it = 0; it < 8; ++it)
      A_lds[tid + 256 * it] = src[tid + 256 * it];
    __syncthreads();

    const int qrow0 = k0 / 8 + h * 32;
#pragma unroll
    for (int g2 = 0; g2 < 2; ++g2) {
      f32x4 gacc[2][2] = {};
#pragma unroll
      for (int ksl = 0; ksl < 4; ++ksl) {
        const int ks = g2 * 4 + ksl;
        uint32_t q[2];
        const int qrow = qrow0 + ks * 4 + quad;
#pragma unroll
        for (int j = 0; j < 2; ++j)
          q[j] = (uint32_t)qweight[(size_t)qrow * OUT + ncol + 16 * j];
        bf16x8 af[2];
#pragma unroll
        for (int i2 = 0; i2 < 2; ++i2)
          af[i2] = *(const bf16x8*)&A_lds[(ks * 4 + 2 * wm + i2) * 64 + lane];
#pragma unroll
        for (int j = 0; j < 2; ++j) {
          uint32_t p[4];
          p[0] = ( q[j]        & 0x000F000Fu) | 0x43004300u;
          p[1] = ((q[j] >>  4) & 0x000F000Fu) | 0x43004300u;
          p[2] = ((q[j] >>  8) & 0x000F000Fu) | 0x43004300u;
          p[3] = ((q[j] >> 12) & 0x000F000Fu) | 0x43004300u;
          bf16x8 bfr = *(bf16x8*)p;
#pragma unroll
          for (int i2 = 0; i2 < 2; ++i2)
            gacc[i2][j] = __builtin_amdgcn_mfma_f32_16x16x32_bf16(af[i2], bfr, gacc[i2][j], 0, 0, 0);
        }
      }
      // fold group: macc += s*gacc - s*(128+z)*rowsum
      const int g = (k0 >> 7) + h * 2 + g2;
      float Sv[2][4];
#pragma unroll
      for (int i2 = 0; i2 < 2; ++i2)
#pragma unroll
        for (int r = 0; r < 4; ++r)
          Sv[i2][r] = xsum[g * 64 + 32 * wm + 16 * i2 + 4 * quad + r];
#pragma unroll
      for (int j = 0; j < 2; ++j) {
        const float s = scales[g * OUT + ncol + 16 * j];
        const float z = zeros[g * OUT + ncol + 16 * j];
        const float u = s * (128.0f + z);
#pragma unroll
        for (int i2 = 0; i2 < 2; ++i2)
#pragma unroll
          for (int r = 0; r < 4; ++r)
            macc[i2][j][r] = fmaf(s, gacc[i2][j][r], fmaf(-u, Sv[i2][r], macc[i2][j][r]));
      }
    }
  }

  // partial stores (coalesced 64B per quad-row)
  float* Pp = P + (size_t)sp * (BATCH * OUT);
#pragma unroll
  for (int i2 = 0; i2 < 2; ++i2)
#pragma unroll
    for (int r = 0; r < 4; ++r) {
      const int m = 32 * wm + 16 * i2 + 4 * quad + r;
#pragma unroll
      for (int j = 0; j < 2; ++j)
        Pp[(size_t)m * OUT + ncol + 16 * j] = macc[i2][j][r];
    }

  // fused tail reduce: last split block for this N-tile sums the partials
  __threadfence();
  __syncthreads();
  if (tid == 0) last_flag = (atomicAdd(&cnt[blockIdx.x], 1) == SPLITK - 1);
  __syncthreads();
  if (last_flag) {
    __threadfence();
    const float4* P4 = (const float4*)P;
    float4* out4 = (float4*)out;
#pragma unroll
    for (int slot = tid; slot < 1024; slot += 256) {
      const int m = slot >> 4, c = slot & 15;
      const size_t off = (size_t)m * (OUT / 4) + (n0 >> 2) + c;
      float4 a = P4[off];
#pragma unroll
      for (int s2 = 1; s2 < SPLITK; ++s2) {
        float4 b = P4[off + (size_t)s2 * (BATCH * OUT / 4)];
        a.x += b.x; a.y += b.y; a.z += b.z; a.w += b.w;
      }
      out4[off] = a;
    }
  }
}

extern "C" void kernel_launch(void* const* d_in, const int* in_sizes, int n_in,
                              void* d_out, int out_size, void* d_ws, size_t ws_size,
                              hipStream_t stream) {
  const float* x = (const float*)d_in[0];
  const int* qweight = (const int*)d_in[1];
  const float* scales = (const float*)d_in[2];
  const float* zeros = (const float*)d_in[3];
  float* out = (float*)d_out;
  ushort* xbf = (ushort*)d_ws;                       // 512 KB, frag-major
  float* xsum = (float*)((char*)d_ws + (1 << 19));   // 8 KB
  int* cnt = (int*)((char*)d_ws + (1 << 19) + 8192); // 688 B tickets
  float* P = (float*)((char*)d_ws + (1 << 20));      // 11.25 MB partials

  cvt_frag_kernel<<<32, 256, 0, stream>>>(x, xbf, xsum, cnt);
  mpq_gemm<<<dim3(GRID_N, SPLITK), 256, 0, stream>>>(xbf, qweight, scales, zeros, xsum, P, cnt, out);
}

// Round 7
// 94.893 us; speedup vs baseline: 2.0667x; 2.0667x over previous
//
#include <hip/hip_runtime.h>
#include <stdint.h>

// W4 group-quantized linear, v6: v5's SPLITK=4 gemm, fused tail REMOVED.
// (v5 lesson: __threadfence() on gfx950 = device-scope fence = L2
//  writeback/invalidate per block -> 688 blocks serialized ~135us. Never
//  use device fences in the hot path on CDNA4; separate dispatch instead.)
//  * Verified math: biased-nibble MFMA B (bf16 0x4300|n == 128+n exact),
//    k-perm sigma=[0,4,1,5,2,6,3,7] on both A (at cvt) and B (free),
//    per-group fold x.W = s*gacc - s*(128+z)*xsum (rounded-bf16 row sums).
//  * gemm: grid (172,4), 256 thr = 4 waves, wave tile M32xN32, K=1024/block
//    in 4 stages of 256 (32KB A LDS each). 2752 waves = 2.7/SIMD.
//  * SPLITK=4 partials (11.25 MB) + separate reduce dispatch (L2/L3-hot).

#define IN 4096
#define OUT 11008
#define BATCH 64
#define SPLITK 4
#define KSPL 1024
#define BN 64
#define GRID_N 172

typedef __attribute__((ext_vector_type(8))) __bf16 bf16x8;
typedef __attribute__((ext_vector_type(4))) float f32x4;

static __device__ __forceinline__ ushort f2bf(float f) {
  uint32_t u = __float_as_uint(f);
  u += 0x7fff + ((u >> 16) & 1); // RNE
  return (ushort)(u >> 16);
}
static __device__ __forceinline__ float bf2f(ushort h) {
  return __uint_as_float(((uint32_t)h) << 16);
}

// One block per quant group g. Thread t: row m = t>>2, quarter q = t&3.
// Emits xbf in A-frag-major kperm order + exact xsum[g][m] (shfl, no atomics).
__global__ void cvt_frag_kernel(const float* __restrict__ x,
                                ushort* __restrict__ xbf,
                                float* __restrict__ xsum) {
  const int g = blockIdx.x;
  const int t = threadIdx.x;
  const int m = t >> 2;
  const int q = t & 3;
  const int ks = 4 * g + q; // 32-wide k slab
  const int kb = 32 * ks;

  float v[32];
  ushort vb[32];
  float s = 0.f;
#pragma unroll
  for (int c4 = 0; c4 < 8; ++c4) {
    float4 f = *(const float4*)&x[m * IN + kb + 4 * c4];
    v[4 * c4 + 0] = f.x; v[4 * c4 + 1] = f.y; v[4 * c4 + 2] = f.z; v[4 * c4 + 3] = f.w;
  }
#pragma unroll
  for (int c = 0; c < 32; ++c) {
    vb[c] = f2bf(v[c]);
    s += bf2f(vb[c]);
  }
  const int i = m >> 4, mlane = m & 15;
#pragma unroll
  for (int qd = 0; qd < 4; ++qd) {
    ushort o[8];
    o[0] = vb[8 * qd + 0]; o[1] = vb[8 * qd + 4];
    o[2] = vb[8 * qd + 1]; o[3] = vb[8 * qd + 5];
    o[4] = vb[8 * qd + 2]; o[5] = vb[8 * qd + 6];
    o[6] = vb[8 * qd + 3]; o[7] = vb[8 * qd + 7];
    const int flat = (ks * 4 + i) * 64 + qd * 16 + mlane;
    *(uint4*)&xbf[flat * 8] = *(uint4*)o;
  }
  s += __shfl_xor(s, 1);
  s += __shfl_xor(s, 2);
  if (q == 0) xsum[g * 64 + m] = s;
}

__global__ __launch_bounds__(256, 3) void mpq_gemm(
    const ushort* __restrict__ xbf,    // frag-major A
    const int* __restrict__ qweight,   // [512][11008]
    const float* __restrict__ scales,  // [32][11008]
    const float* __restrict__ zeros,   // [32][11008]
    const float* __restrict__ xsum,    // [32][64]
    float* __restrict__ P)             // [4][64][11008] partials
{
  __shared__ uint4 A_lds[2048]; // 32 KB: [ksl 0..7][i 0..3][lane]

  const int n0 = blockIdx.x * BN;
  const int sp = blockIdx.y;
  const int k0 = sp * KSPL;
  const int tid = threadIdx.x;
  const int lane = tid & 63;
  const int w = tid >> 6;
  const int wm = w >> 1, wn = w & 1;     // M half / N half
  const int mlane = lane & 15, quad = lane >> 4;
  const int ncol = n0 + 32 * wn + mlane; // col base (j adds 16j)

  f32x4 macc[2][2] = {};

  const uint4* gA = (const uint4*)xbf + (size_t)(k0 / 32) * 256;

  for (int h = 0; h < 4; ++h) {
    __syncthreads(); // previous stage's A reads complete
    const uint4* src = gA + (size_t)h * 2048;
#pragma unroll
    for (int it = 0; it < 8; ++it)
      A_lds[tid + 256 * it] = src[tid + 256 * it];
    __syncthreads();

    const int qrow0 = k0 / 8 + h * 32;
#pragma unroll
    for (int g2 = 0; g2 < 2; ++g2) {
      f32x4 gacc[2][2] = {};
#pragma unroll
      for (int ksl = 0; ksl < 4; ++ksl) {
        const int ks = g2 * 4 + ksl;
        uint32_t q[2];
        const int qrow = qrow0 + ks * 4 + quad;
#pragma unroll
        for (int j = 0; j < 2; ++j)
          q[j] = (uint32_t)qweight[(size_t)qrow * OUT + ncol + 16 * j];
        bf16x8 af[2];
#pragma unroll
        for (int i2 = 0; i2 < 2; ++i2)
          af[i2] = *(const bf16x8*)&A_lds[(ks * 4 + 2 * wm + i2) * 64 + lane];
#pragma unroll
        for (int j = 0; j < 2; ++j) {
          uint32_t p[4];
          p[0] = ( q[j]        & 0x000F000Fu) | 0x43004300u;
          p[1] = ((q[j] >>  4) & 0x000F000Fu) | 0x43004300u;
          p[2] = ((q[j] >>  8) & 0x000F000Fu) | 0x43004300u;
          p[3] = ((q[j] >> 12) & 0x000F000Fu) | 0x43004300u;
          bf16x8 bfr = *(bf16x8*)p;
#pragma unroll
          for (int i2 = 0; i2 < 2; ++i2)
            gacc[i2][j] = __builtin_amdgcn_mfma_f32_16x16x32_bf16(af[i2], bfr, gacc[i2][j], 0, 0, 0);
        }
      }
      // fold group: macc += s*gacc - s*(128+z)*rowsum
      const int g = (k0 >> 7) + h * 2 + g2;
      float Sv[2][4];
#pragma unroll
      for (int i2 = 0; i2 < 2; ++i2)
#pragma unroll
        for (int r = 0; r < 4; ++r)
          Sv[i2][r] = xsum[g * 64 + 32 * wm + 16 * i2 + 4 * quad + r];
#pragma unroll
      for (int j = 0; j < 2; ++j) {
        const float s = scales[g * OUT + ncol + 16 * j];
        const float z = zeros[g * OUT + ncol + 16 * j];
        const float u = s * (128.0f + z);
#pragma unroll
        for (int i2 = 0; i2 < 2; ++i2)
#pragma unroll
          for (int r = 0; r < 4; ++r)
            macc[i2][j][r] = fmaf(s, gacc[i2][j][r], fmaf(-u, Sv[i2][r], macc[i2][j][r]));
      }
    }
  }

  // partial stores (coalesced 64B per quad-row)
  float* Pp = P + (size_t)sp * (BATCH * OUT);
#pragma unroll
  for (int i2 = 0; i2 < 2; ++i2)
#pragma unroll
    for (int r = 0; r < 4; ++r) {
      const int m = 32 * wm + 16 * i2 + 4 * quad + r;
#pragma unroll
      for (int j = 0; j < 2; ++j)
        Pp[(size_t)m * OUT + ncol + 16 * j] = macc[i2][j][r];
    }
}

__global__ void reduce_kernel(const float* __restrict__ P, float* __restrict__ out) {
  const int t = blockIdx.x * blockDim.x + threadIdx.x; // 176128 float4-slots
  float4 a = ((const float4*)P)[t];
#pragma unroll
  for (int s = 1; s < SPLITK; ++s) {
    float4 b = ((const float4*)P)[t + (size_t)s * (BATCH * OUT / 4)];
    a.x += b.x; a.y += b.y; a.z += b.z; a.w += b.w;
  }
  ((float4*)out)[t] = a;
}

extern "C" void kernel_launch(void* const* d_in, const int* in_sizes, int n_in,
                              void* d_out, int out_size, void* d_ws, size_t ws_size,
                              hipStream_t stream) {
  const float* x = (const float*)d_in[0];
  const int* qweight = (const int*)d_in[1];
  const float* scales = (const float*)d_in[2];
  const float* zeros = (const float*)d_in[3];
  float* out = (float*)d_out;
  ushort* xbf = (ushort*)d_ws;                      // 512 KB, frag-major
  float* xsum = (float*)((char*)d_ws + (1 << 19));  // 8 KB
  float* P = (float*)((char*)d_ws + (1 << 20));     // 11.25 MB partials

  cvt_frag_kernel<<<32, 256, 0, stream>>>(x, xbf, xsum);
  mpq_gemm<<<dim3(GRID_N, SPLITK), 256, 0, stream>>>(xbf, qweight, scales, zeros, xsum, P);
  reduce_kernel<<<BATCH * OUT / 4 / 256, 256, 0, stream>>>(P, out);
}